// Round 2
// baseline (97.361 us; speedup 1.0000x reference)
//
#include <hip/hip_runtime.h>
#include <math.h>

#define NF 1024
#define DIM 256
#define BATCH 2048
#define K 512            // interleaved (x^2, x) -> 2*DIM
#define BMF 16           // batch rows per k_full block
#define GX (BATCH / BMF) // 128 blocks

// ws layout:
//   [0, 1MB)    : Bb bf16[NF][K]  rows: (s2, -2*s2*mu) interleaved per dim
//   [1MB, +4KB) : c  float[NF]
#define WS_C_OFF (NF * K * 2)

typedef __attribute__((ext_vector_type(8))) short short8;   // 8 bf16
typedef __attribute__((ext_vector_type(4))) float f32x4;    // MFMA acc

__device__ __forceinline__ unsigned short f2bf(float f) {
    unsigned u = __float_as_uint(f);
    u += 0x7fffu + ((u >> 16) & 1u);       // RNE
    return (unsigned short)(u >> 16);
}

// ---------------------------------------------------------------------------
// K1: one block per formula f -> Bb row (coalesced u32 stores) + c[f].
__global__ __launch_bounds__(256) void k_prep(const float* __restrict__ mu,
                                              const float* __restrict__ sigma,
                                              unsigned int* __restrict__ Bb32,
                                              float* __restrict__ c) {
    const int t = threadIdx.x;
    const int f = blockIdx.x;
    const float m = mu[f * DIM + t];
    const float s = sigma[f * DIM + t];
    const float s2 = s * s;
    Bb32[f * DIM + t] = (unsigned)f2bf(s2) | ((unsigned)f2bf(-2.0f * s2 * m) << 16);

    float cp = s2 * m * m;
    #pragma unroll
    for (int off = 32; off > 0; off >>= 1) cp += __shfl_down(cp, off, 64);
    __shared__ float red[4];
    const int lane = t & 63, wv = t >> 6;
    if (lane == 0) red[wv] = cp;
    __syncthreads();
    if (t == 0) c[f] = red[0] + red[1] + red[2] + red[3];
}

// ---------------------------------------------------------------------------
// K2: fused GEMM + epilogue + row-softmax normalization.
// 128 blocks x 512 threads (8 waves). Block = 16 batch rows x ALL 1024
// formulas, so the softmax denominator is block-local: p stays in registers,
// out is written exactly once, no k_norm pass.
//   - A (16 x 512 bf16, 16 KB) packed from x into XOR-swizzled LDS slots:
//     slot(row,kc) = row*64 + (kc ^ (row&7)); ds_read_b128 then 2-way on
//     banks (free). Each x-row used by exactly one block -> no Ab in HBM.
//   - B fragments are wave-disjoint (wave w owns cols [w*128,+128)) -> no
//     reuse, so load global->reg directly, ping-pong double-buffered.
__global__ __launch_bounds__(512, 2) void k_full(const float* __restrict__ x,
                                                 const ushort* __restrict__ Bb,
                                                 const float* __restrict__ c,
                                                 const float* __restrict__ temp,
                                                 float* __restrict__ out) {
    const int t = threadIdx.x;
    const int w = t >> 6;          // wave 0..7
    const int lane = t & 63;
    const int m16 = lane & 15;
    const int q = lane >> 4;       // 0..3
    const int r0 = blockIdx.x * BMF;

    __shared__ __align__(16) ushort ldsA[BMF * K];   // 16 KB, swizzled slots
    __shared__ float wsum[8][BMF];
    __shared__ float rowInv[BMF];

    // ---- pack A: 1024 units of (row, kc-chunk of 4 dims) ----
    #pragma unroll
    for (int h = 0; h < 2; ++h) {
        const int u = h * 512 + t;
        const int row = u >> 6, kc = u & 63;
        const float4 v = *(const float4*)&x[(r0 + row) * DIM + kc * 4];
        uint4 pk;
        pk.x = (unsigned)f2bf(v.x * v.x) | ((unsigned)f2bf(v.x) << 16);
        pk.y = (unsigned)f2bf(v.y * v.y) | ((unsigned)f2bf(v.y) << 16);
        pk.z = (unsigned)f2bf(v.z * v.z) | ((unsigned)f2bf(v.z) << 16);
        pk.w = (unsigned)f2bf(v.w * v.w) | ((unsigned)f2bf(v.w) << 16);
        *(uint4*)&ldsA[(row * 64 + (kc ^ (row & 7))) * 8] = pk;
    }
    __syncthreads();

    f32x4 acc[8];
    #pragma unroll
    for (int ct = 0; ct < 8; ++ct) acc[ct] = (f32x4){0.f, 0.f, 0.f, 0.f};

    // lane's B base: formula row (w*128 + ct*16 + m16), k-offset q*8
    const ushort* bbase = Bb + (w * 128 + m16) * K + q * 8;

    // ---- K loop: 16 steps of 32, reg-double-buffered B ----
    short8 b0[8], b1[8];
    #pragma unroll
    for (int ct = 0; ct < 8; ++ct)
        b0[ct] = *(const short8*)(bbase + ct * 16 * K);

    #pragma unroll 1
    for (int n = 0; n < 14; n += 2) {
        #pragma unroll
        for (int ct = 0; ct < 8; ++ct)
            b1[ct] = *(const short8*)(bbase + ct * 16 * K + (n + 1) * 32);
        {
            const int kcq = (n << 2) + q;    // (n*32)/8 + q
            const short8 av = *(const short8*)&ldsA[(m16 * 64 + (kcq ^ (m16 & 7))) * 8];
            #pragma unroll
            for (int ct = 0; ct < 8; ++ct)
                acc[ct] = __builtin_amdgcn_mfma_f32_16x16x32_bf16(av, b0[ct], acc[ct], 0, 0, 0);
        }
        #pragma unroll
        for (int ct = 0; ct < 8; ++ct)
            b0[ct] = *(const short8*)(bbase + ct * 16 * K + (n + 2) * 32);
        {
            const int kcq = ((n + 1) << 2) + q;
            const short8 av = *(const short8*)&ldsA[(m16 * 64 + (kcq ^ (m16 & 7))) * 8];
            #pragma unroll
            for (int ct = 0; ct < 8; ++ct)
                acc[ct] = __builtin_amdgcn_mfma_f32_16x16x32_bf16(av, b1[ct], acc[ct], 0, 0, 0);
        }
    }
    // tail: n = 14, 15
    #pragma unroll
    for (int ct = 0; ct < 8; ++ct)
        b1[ct] = *(const short8*)(bbase + ct * 16 * K + 15 * 32);
    {
        const int kcq = 56 + q;
        const short8 av = *(const short8*)&ldsA[(m16 * 64 + (kcq ^ (m16 & 7))) * 8];
        #pragma unroll
        for (int ct = 0; ct < 8; ++ct)
            acc[ct] = __builtin_amdgcn_mfma_f32_16x16x32_bf16(av, b0[ct], acc[ct], 0, 0, 0);
    }
    {
        const int kcq = 60 + q;
        const short8 av = *(const short8*)&ldsA[(m16 * 64 + (kcq ^ (m16 & 7))) * 8];
        #pragma unroll
        for (int ct = 0; ct < 8; ++ct)
            acc[ct] = __builtin_amdgcn_mfma_f32_16x16x32_bf16(av, b1[ct], acc[ct], 0, 0, 0);
    }

    // ---- epilogue: p = exp(g*exp(-dist)) in-register ----
    const float g = 1.0f / (1.0f + __expf(-temp[0]));
    float s[4] = {0.f, 0.f, 0.f, 0.f};
    #pragma unroll
    for (int ct = 0; ct < 8; ++ct) {
        const float cn = c[w * 128 + ct * 16 + m16];
        #pragma unroll
        for (int i = 0; i < 4; ++i) {
            const float dist2 = acc[ct][i] + cn;
            const float dist = sqrtf(fmaxf(dist2, 0.0f));
            const float p = __expf(g * __expf(-dist));
            acc[ct][i] = p;          // keep p in the acc registers
            s[i] += p;
        }
    }
    // reduce over the 16 m16-lanes (q stays fixed) -> wave-partial row sums
    #pragma unroll
    for (int i = 0; i < 4; ++i) {
        #pragma unroll
        for (int mask = 1; mask < 16; mask <<= 1)
            s[i] += __shfl_xor(s[i], mask, 64);
    }
    if (m16 == 0) {
        #pragma unroll
        for (int i = 0; i < 4; ++i) wsum[w][q * 4 + i] = s[i];
    }
    __syncthreads();
    if (t < BMF) {
        float ssum = 0.f;
        #pragma unroll
        for (int ww = 0; ww < 8; ++ww) ssum += wsum[ww][t];
        rowInv[t] = 1.0f / ssum;
    }
    __syncthreads();

    // ---- normalize + single coalesced store of out ----
    float inv[4];
    #pragma unroll
    for (int i = 0; i < 4; ++i) inv[i] = rowInv[q * 4 + i];
    #pragma unroll
    for (int ct = 0; ct < 8; ++ct) {
        const int fcol = w * 128 + ct * 16 + m16;
        #pragma unroll
        for (int i = 0; i < 4; ++i)
            out[(r0 + q * 4 + i) * NF + fcol] = acc[ct][i] * inv[i];
    }
}

extern "C" void kernel_launch(void* const* d_in, const int* in_sizes, int n_in,
                              void* d_out, int out_size, void* d_ws, size_t ws_size,
                              hipStream_t stream) {
    const float* x     = (const float*)d_in[0];
    const float* mu    = (const float*)d_in[1];
    const float* sigma = (const float*)d_in[2];
    const float* temp  = (const float*)d_in[3];
    float* out = (float*)d_out;

    char* ws = (char*)d_ws;
    ushort* Bb = (ushort*)ws;
    float*  c  = (float*)(ws + WS_C_OFF);

    k_prep<<<NF, 256, 0, stream>>>(mu, sigma, (unsigned int*)Bb, c);
    k_full<<<GX, 512, 0, stream>>>(x, Bb, c, temp, out);
}

// Round 3
// 85.776 us; speedup vs baseline: 1.1351x; 1.1351x over previous
//
#include <hip/hip_runtime.h>
#include <math.h>

#define NF 1024
#define DIM 256
#define BATCH 2048
#define K 512            // interleaved (x^2, x) -> 2*DIM
#define BMF 16           // batch rows per k_full block
#define GX (BATCH / BMF) // 128 blocks
#define KS 32            // k elems per staged B step
#define NSTEP (K / KS)   // 16

// ws layout:
//   [0, 1MB)    : Bb bf16, STEP-MAJOR: [NSTEP][NF][KS]  (so each K-step's
//                 64 KB staging slice is contiguous -> perfectly coalesced
//                 global_load_lds, linear LDS dest)
//   [1MB, +4KB) : c  float[NF]
#define WS_C_OFF (NF * K * 2)

typedef __attribute__((ext_vector_type(8))) short short8;   // 8 bf16
typedef __attribute__((ext_vector_type(4))) float f32x4;    // MFMA acc

__device__ __forceinline__ unsigned short f2bf(float f) {
    unsigned u = __float_as_uint(f);
    u += 0x7fffu + ((u >> 16) & 1u);       // RNE
    return (unsigned short)(u >> 16);
}

// async global->LDS, 16B per lane; LDS dest must be uniform-base + lane*16
__device__ __forceinline__ void gl_lds16(const ushort* g, ushort* l) {
    __builtin_amdgcn_global_load_lds(
        (const __attribute__((address_space(1))) void*)g,
        (__attribute__((address_space(3))) void*)l, 16, 0, 0);
}

// ---------------------------------------------------------------------------
// K1: one block per formula f. Writes Bb in step-major layout + c[f].
// k-elems (2t, 2t+1) live in step s = t>>4, u32 slot j = t&15.
__global__ __launch_bounds__(256) void k_prep(const float* __restrict__ mu,
                                              const float* __restrict__ sigma,
                                              unsigned int* __restrict__ Bb32,
                                              float* __restrict__ c) {
    const int t = threadIdx.x;             // dim d
    const int f = blockIdx.x;
    const float m = mu[f * DIM + t];
    const float s = sigma[f * DIM + t];
    const float s2 = s * s;
    Bb32[(t >> 4) * (NF * 16) + f * 16 + (t & 15)] =
        (unsigned)f2bf(s2) | ((unsigned)f2bf(-2.0f * s2 * m) << 16);

    float cp = s2 * m * m;
    #pragma unroll
    for (int off = 32; off > 0; off >>= 1) cp += __shfl_down(cp, off, 64);
    __shared__ float red[4];
    const int lane = t & 63, wv = t >> 6;
    if (lane == 0) red[wv] = cp;
    __syncthreads();
    if (t == 0) c[f] = red[0] + red[1] + red[2] + red[3];
}

// ---------------------------------------------------------------------------
// K2: fused GEMM + epilogue + row-softmax normalization.
// 128 blocks x 512 threads (8 waves). Block = 16 batch rows x ALL 1024
// formulas -> softmax denominator block-local, out written exactly once.
//   A (16x512 bf16, 16 KB): packed from x into XOR-swizzled slots
//     slot(row,kc) = row*64 + (kc ^ (row&7)) -> conflict-light ds_read_b128.
//   B: double-buffered LDS staging via global_load_lds, 64 KB per K-step,
//     contiguous source (step-major Bb) + linear dest. Fragment reads are
//     contiguous 1 KB per (wave,ct) -> no swizzle needed.
__global__ __launch_bounds__(512, 2) void k_full(const float* __restrict__ x,
                                                 const ushort* __restrict__ Bb,
                                                 const float* __restrict__ c,
                                                 const float* __restrict__ temp,
                                                 float* __restrict__ out) {
    const int t = threadIdx.x;
    const int w = t >> 6;          // wave 0..7
    const int lane = t & 63;
    const int m16 = lane & 15;
    const int q = lane >> 4;       // 0..3
    const int r0 = blockIdx.x * BMF;

    __shared__ __align__(16) ushort ldsA[BMF * K];        // 16 KB, swizzled
    __shared__ __align__(16) ushort ldsB[2][NF * KS];     // 2 x 64 KB, linear
    __shared__ float wsum[8][BMF];
    __shared__ float rowInv[BMF];

    // ---- pack A: 1024 units of (row, kc-chunk of 4 dims) ----
    #pragma unroll
    for (int h = 0; h < 2; ++h) {
        const int u = h * 512 + t;
        const int row = u >> 6, kc = u & 63;
        const float4 v = *(const float4*)&x[(r0 + row) * DIM + kc * 4];
        uint4 pk;
        pk.x = (unsigned)f2bf(v.x * v.x) | ((unsigned)f2bf(v.x) << 16);
        pk.y = (unsigned)f2bf(v.y * v.y) | ((unsigned)f2bf(v.y) << 16);
        pk.z = (unsigned)f2bf(v.z * v.z) | ((unsigned)f2bf(v.z) << 16);
        pk.w = (unsigned)f2bf(v.w * v.w) | ((unsigned)f2bf(v.w) << 16);
        *(uint4*)&ldsA[(row * 64 + (kc ^ (row & 7))) * 8] = pk;
    }

    f32x4 acc[8];
    #pragma unroll
    for (int ct = 0; ct < 8; ++ct) acc[ct] = (f32x4){0.f, 0.f, 0.f, 0.f};

    // ---- stage step 0 ----
    #pragma unroll
    for (int i = 0; i < 8; ++i) {
        const int u = i * 512 + t;                  // 16B unit 0..4095
        gl_lds16(Bb + u * 8, &ldsB[0][u * 8]);
    }

    // ---- K loop: one barrier per step; stage next, compute current ----
    #pragma unroll 1
    for (int s = 0; s < NSTEP; ++s) {
        __syncthreads();   // vmcnt(0) drain: buf[s&1] ready; prev reads retired
        if (s + 1 < NSTEP) {
            const ushort* src = Bb + (s + 1) * (NF * KS);
            ushort* dst = &ldsB[(s + 1) & 1][0];
            #pragma unroll
            for (int i = 0; i < 8; ++i) {
                const int u = i * 512 + t;
                gl_lds16(src + u * 8, dst + u * 8);
            }
        }
        const ushort* bcur = &ldsB[s & 1][0];
        const int kcq = s * 4 + q;
        const short8 av = *(const short8*)&ldsA[(m16 * 64 + (kcq ^ (m16 & 7))) * 8];
        #pragma unroll
        for (int ct = 0; ct < 8; ++ct) {
            const int f = w * 128 + ct * 16 + m16;
            const short8 bv = *(const short8*)&bcur[f * KS + q * 8];
            acc[ct] = __builtin_amdgcn_mfma_f32_16x16x32_bf16(av, bv, acc[ct], 0, 0, 0);
        }
    }

    // ---- epilogue: p = exp(g*exp(-dist)) in-register ----
    const float g = 1.0f / (1.0f + __expf(-temp[0]));
    float s4[4] = {0.f, 0.f, 0.f, 0.f};
    #pragma unroll
    for (int ct = 0; ct < 8; ++ct) {
        const float cn = c[w * 128 + ct * 16 + m16];
        #pragma unroll
        for (int i = 0; i < 4; ++i) {
            const float dist2 = acc[ct][i] + cn;
            const float dist = sqrtf(fmaxf(dist2, 0.0f));
            const float p = __expf(g * __expf(-dist));
            acc[ct][i] = p;          // keep p in registers
            s4[i] += p;
        }
    }
    // reduce over the 16 m16-lanes (q fixed) -> wave-partial row sums
    #pragma unroll
    for (int i = 0; i < 4; ++i) {
        #pragma unroll
        for (int mask = 1; mask < 16; mask <<= 1)
            s4[i] += __shfl_xor(s4[i], mask, 64);
    }
    if (m16 == 0) {
        #pragma unroll
        for (int i = 0; i < 4; ++i) wsum[w][q * 4 + i] = s4[i];
    }
    __syncthreads();
    if (t < BMF) {
        float ssum = 0.f;
        #pragma unroll
        for (int ww = 0; ww < 8; ++ww) ssum += wsum[ww][t];
        rowInv[t] = 1.0f / ssum;
    }
    __syncthreads();

    // ---- normalize + single coalesced store of out ----
    float inv[4];
    #pragma unroll
    for (int i = 0; i < 4; ++i) inv[i] = rowInv[q * 4 + i];
    #pragma unroll
    for (int ct = 0; ct < 8; ++ct) {
        const int fcol = w * 128 + ct * 16 + m16;
        #pragma unroll
        for (int i = 0; i < 4; ++i)
            out[(r0 + q * 4 + i) * NF + fcol] = acc[ct][i] * inv[i];
    }
}

extern "C" void kernel_launch(void* const* d_in, const int* in_sizes, int n_in,
                              void* d_out, int out_size, void* d_ws, size_t ws_size,
                              hipStream_t stream) {
    const float* x     = (const float*)d_in[0];
    const float* mu    = (const float*)d_in[1];
    const float* sigma = (const float*)d_in[2];
    const float* temp  = (const float*)d_in[3];
    float* out = (float*)d_out;

    char* ws = (char*)d_ws;
    ushort* Bb = (ushort*)ws;
    float*  c  = (float*)(ws + WS_C_OFF);

    k_prep<<<NF, 256, 0, stream>>>(mu, sigma, (unsigned int*)Bb, c);
    k_full<<<GX, 512, 0, stream>>>(x, Bb, c, temp, out);
}

// Round 5
// 82.701 us; speedup vs baseline: 1.1773x; 1.0372x over previous
//
#include <hip/hip_runtime.h>
#include <math.h>

#define NF 1024
#define DIM 256
#define BATCH 2048
#define K 512              // interleaved (x^2, x) -> 2*DIM
#define BMF 16             // batch rows per k_main block
#define NCC 4              // formula chunks
#define CF (NF / NCC)      // 256 formulas per chunk
#define KS 32              // k elems per staged step
#define NSTEP (K / KS)     // 16

// ws layout:
//   [0, 1MB)       : Bb bf16 [NCC][NSTEP][4(q)][CF][8]  (per (chunk,step) the
//                    16 KB slice is contiguous -> coalesced global_load_lds,
//                    linear LDS dest, 2-way-bank fragment reads)
//   [1MB, +4KB)    : c  float[NF]
//   [1MB+4KB, +32K): rowPartial float[NCC][BATCH]
#define WS_C_OFF  (NF * K * 2)
#define WS_RP_OFF (WS_C_OFF + NF * 4)

typedef __attribute__((ext_vector_type(8))) short short8;   // 8 bf16
typedef __attribute__((ext_vector_type(4))) float f32x4;    // MFMA acc

__device__ __forceinline__ unsigned short f2bf(float f) {
    unsigned u = __float_as_uint(f);
    u += 0x7fffu + ((u >> 16) & 1u);       // RNE
    return (unsigned short)(u >> 16);
}

// async global->LDS, 16B per lane; LDS dest must be uniform-base + lane*16
__device__ __forceinline__ void gl_lds16(const ushort* g, ushort* l) {
    __builtin_amdgcn_global_load_lds(
        (const __attribute__((address_space(1))) void*)g,
        (__attribute__((address_space(3))) void*)l, 16, 0, 0);
}

// ---------------------------------------------------------------------------
// K1: 256 blocks x 256 threads. Wave = one formula f; lane sq = (s,q) pair
// handles dims d0 = sq*4 .. +3. Loads: consecutive lanes -> consecutive
// float4 (fully coalesced). Store: one uint4 per thread into the step-major
// Bb layout. c[f] via in-wave shuffle reduce (no LDS, no barrier).
__global__ __launch_bounds__(256) void k_prep(const float* __restrict__ mu,
                                              const float* __restrict__ sigma,
                                              uint4* __restrict__ Bb4,
                                              float* __restrict__ c) {
    const int t = threadIdx.x;
    const int f = blockIdx.x * 4 + (t >> 6);
    const int sq = t & 63;                 // s = sq>>2, q = sq&3
    const float4 mv = *(const float4*)&mu[f * DIM + sq * 4];
    const float4 sv = *(const float4*)&sigma[f * DIM + sq * 4];

    uint4 pk; float cp = 0.f;
    {
        const float s2x = sv.x * sv.x;
        pk.x = (unsigned)f2bf(s2x) | ((unsigned)f2bf(-2.0f * s2x * mv.x) << 16);
        cp += s2x * mv.x * mv.x;
        const float s2y = sv.y * sv.y;
        pk.y = (unsigned)f2bf(s2y) | ((unsigned)f2bf(-2.0f * s2y * mv.y) << 16);
        cp += s2y * mv.y * mv.y;
        const float s2z = sv.z * sv.z;
        pk.z = (unsigned)f2bf(s2z) | ((unsigned)f2bf(-2.0f * s2z * mv.z) << 16);
        cp += s2z * mv.z * mv.z;
        const float s2w = sv.w * sv.w;
        pk.w = (unsigned)f2bf(s2w) | ((unsigned)f2bf(-2.0f * s2w * mv.w) << 16);
        cp += s2w * mv.w * mv.w;
    }
    // uint4 index: cc*16384 + s*1024 + q*256 + fl   (cc = f>>8, fl = f&255)
    Bb4[(f >> 8) * 16384 + (sq >> 2) * 1024 + (sq & 3) * 256 + (f & 255)] = pk;

    #pragma unroll
    for (int off = 32; off > 0; off >>= 1) cp += __shfl_down(cp, off, 64);
    if ((t & 63) == 0) c[f] = cp;
}

// ---------------------------------------------------------------------------
// K2: grid (128 row-groups, 4 formula chunks) = 512 blocks, 256 threads
// (4 waves), 2 blocks/CU -> cross-block latency hiding at the barriers.
// Block = 16 batch rows x 256 formulas. Wave w owns formulas
// [cc*256 + w*64, +64) as 4 MFMA column tiles.
//   A (16x512 bf16, 16 KB): packed from x into XOR-swizzled slots.
//   B: 16 steps x 16 KB, double-buffered global_load_lds (linear dest).
// Writes unnormalized p to out + per-chunk row sums to rowPartial.
__global__ __launch_bounds__(256, 3) void k_main(const float* __restrict__ x,
                                                 const ushort* __restrict__ Bb,
                                                 const float* __restrict__ c,
                                                 const float* __restrict__ temp,
                                                 float* __restrict__ out,
                                                 float* __restrict__ rowPartial) {
    const int t = threadIdx.x;
    const int w = t >> 6;          // wave 0..3
    const int lane = t & 63;
    const int m16 = lane & 15;
    const int q = lane >> 4;       // 0..3
    const int r0 = blockIdx.x * BMF;
    const int cc = blockIdx.y;

    __shared__ __align__(16) ushort ldsA[BMF * K];      // 16 KB, swizzled
    __shared__ __align__(16) ushort ldsB[2][CF * KS];   // 2 x 16 KB, linear
    __shared__ float wsum[4][BMF];

    // ---- pack A: 1024 units of (row, kc-chunk of 4 dims) ----
    #pragma unroll
    for (int h = 0; h < 4; ++h) {
        const int u = h * 256 + t;
        const int row = u >> 6, kc = u & 63;
        const float4 v = *(const float4*)&x[(r0 + row) * DIM + kc * 4];
        uint4 pk;
        pk.x = (unsigned)f2bf(v.x * v.x) | ((unsigned)f2bf(v.x) << 16);
        pk.y = (unsigned)f2bf(v.y * v.y) | ((unsigned)f2bf(v.y) << 16);
        pk.z = (unsigned)f2bf(v.z * v.z) | ((unsigned)f2bf(v.z) << 16);
        pk.w = (unsigned)f2bf(v.w * v.w) | ((unsigned)f2bf(v.w) << 16);
        *(uint4*)&ldsA[(row * 64 + (kc ^ (row & 7))) * 8] = pk;
    }

    f32x4 acc[4];
    #pragma unroll
    for (int ct = 0; ct < 4; ++ct) acc[ct] = (f32x4){0.f, 0.f, 0.f, 0.f};

    const ushort* bsrc = Bb + cc * (CF * K);   // chunk base (step-major inside)

    // ---- stage step 0 ----
    #pragma unroll
    for (int i = 0; i < 4; ++i) {
        const int u = i * 256 + t;                  // 16B unit 0..1023
        gl_lds16(bsrc + u * 8, &ldsB[0][u * 8]);
    }

    // ---- K loop: stage next, compute current; one barrier per step ----
    #pragma unroll 1
    for (int s = 0; s < NSTEP; ++s) {
        __syncthreads();   // vmcnt drain: buf[s&1] ready; prev reads retired
        if (s + 1 < NSTEP) {
            const ushort* src = bsrc + (s + 1) * (CF * KS);
            ushort* dst = &ldsB[(s + 1) & 1][0];
            #pragma unroll
            for (int i = 0; i < 4; ++i) {
                const int u = i * 256 + t;
                gl_lds16(src + u * 8, dst + u * 8);
            }
        }
        const ushort* bcur = &ldsB[s & 1][0];
        const int kcq = s * 4 + q;
        const short8 av = *(const short8*)&ldsA[(m16 * 64 + (kcq ^ (m16 & 7))) * 8];
        #pragma unroll
        for (int ct = 0; ct < 4; ++ct) {
            const int fl = w * 64 + ct * 16 + m16;          // formula in chunk
            const short8 bv = *(const short8*)&bcur[q * (CF * 8) + fl * 8];
            acc[ct] = __builtin_amdgcn_mfma_f32_16x16x32_bf16(av, bv, acc[ct], 0, 0, 0);
        }
    }

    // ---- epilogue: p = exp(g*exp(-dist)); store + per-chunk row sums ----
    const float g = 1.0f / (1.0f + __expf(-temp[0]));
    float s4[4] = {0.f, 0.f, 0.f, 0.f};
    #pragma unroll
    for (int ct = 0; ct < 4; ++ct) {
        const int fcol = cc * CF + w * 64 + ct * 16 + m16;
        const float cn = c[fcol];
        #pragma unroll
        for (int i = 0; i < 4; ++i) {
            const float dist2 = acc[ct][i] + cn;
            const float dist = sqrtf(fmaxf(dist2, 0.0f));
            const float p = __expf(g * __expf(-dist));
            out[(r0 + q * 4 + i) * NF + fcol] = p;
            s4[i] += p;
        }
    }
    #pragma unroll
    for (int i = 0; i < 4; ++i) {
        #pragma unroll
        for (int mask = 1; mask < 16; mask <<= 1)
            s4[i] += __shfl_xor(s4[i], mask, 64);
    }
    if (m16 == 0) {
        #pragma unroll
        for (int i = 0; i < 4; ++i) wsum[w][q * 4 + i] = s4[i];
    }
    __syncthreads();
    if (t < BMF)
        rowPartial[cc * BATCH + r0 + t] =
            (wsum[0][t] + wsum[1][t]) + (wsum[2][t] + wsum[3][t]);
}

// ---------------------------------------------------------------------------
// K3: block = one batch row; normalize by the 4 chunk-sums.
__global__ __launch_bounds__(256) void k_norm(float* __restrict__ out,
                                              const float* __restrict__ rowPartial) {
    const int row = blockIdx.x;
    const float ssum = (rowPartial[row] + rowPartial[BATCH + row]) +
                       (rowPartial[2 * BATCH + row] + rowPartial[3 * BATCH + row]);
    const float inv = 1.0f / ssum;
    float4* o4 = (float4*)(out + row * NF);
    float4 v = o4[threadIdx.x];
    v.x *= inv; v.y *= inv; v.z *= inv; v.w *= inv;
    o4[threadIdx.x] = v;
}

extern "C" void kernel_launch(void* const* d_in, const int* in_sizes, int n_in,
                              void* d_out, int out_size, void* d_ws, size_t ws_size,
                              hipStream_t stream) {
    const float* x     = (const float*)d_in[0];
    const float* mu    = (const float*)d_in[1];
    const float* sigma = (const float*)d_in[2];
    const float* temp  = (const float*)d_in[3];
    float* out = (float*)d_out;

    char* ws = (char*)d_ws;
    ushort* Bb         = (ushort*)ws;
    float*  c          = (float*)(ws + WS_C_OFF);
    float*  rowPartial = (float*)(ws + WS_RP_OFF);

    k_prep<<<NF / 4, 256, 0, stream>>>(mu, sigma, (uint4*)Bb, c);

    dim3 g2(BATCH / BMF, NCC);
    k_main<<<g2, 256, 0, stream>>>(x, Bb, c, temp, out, rowPartial);

    k_norm<<<BATCH, 256, 0, stream>>>(out, rowPartial);
}